// Round 8
// baseline (64.123 us; speedup 1.0000x reference)
//
#include <hip/hip_runtime.h>
#include <hip/hip_bf16.h>

// x[4096,2048] f32, w[2048,2048] f32, bias[2048] f32, indices = permutation of
// K axis applied to BOTH operands -> cancels out of the einsum; unused.
#define M_DIM 4096
#define N_DIM 2048
#define K_DIM 2048
#define K32   (K_DIM / 32)   // 64 k-chunks per 16-row block

// All-register GEMM: NO LDS, NO barriers. cvt emits operands in a
// fragment-chunked layout; GEMM loads fragments straight to VGPRs with an
// EXPLICIT 1-tile software pipeline (counted vmcnt + sched_barrier fences --
// R7's version let the compiler sink the loads, VGPR=88 proved no prefetch).
// Block 128x128, 4 waves (2x2) of 64x64. Grid 512 = 2 blocks/CU.

typedef __bf16 bf16x8 __attribute__((ext_vector_type(8)));
typedef float f32x4 __attribute__((ext_vector_type(4)));
typedef unsigned short u16x8 __attribute__((ext_vector_type(8)));

__device__ __forceinline__ unsigned short f32_to_bf16_rne(float f) {
  unsigned int u = __float_as_uint(f);
  u += 0x7fffu + ((u >> 16) & 1u);
  return (unsigned short)(u >> 16);
}

// ---- f32 -> bf16 conversion into chunked fragment layout ----
// chunk (rb, kb) = 1 KiB: elem(l, j): row = rb*16 + (l&15),
// k = kb*32 + (l>>4)*8 + j  -> exactly the mfma_16x16x32 operand layout.
__global__ __launch_bounds__(256) void cvt_chunk(
    const float* __restrict__ x, const float* __restrict__ w,
    unsigned short* __restrict__ outx, unsigned short* __restrict__ outw,
    int xslots, int totslots) {
  int s = blockIdx.x * 256 + threadIdx.x;
  if (s >= totslots) return;
  const float* in;
  unsigned short* out;
  int ls = s;
  if (s < xslots) { in = x; out = outx; }
  else            { in = w; out = outw; ls = s - xslots; }
  const int chunk = ls >> 6, l = ls & 63;
  const int rb = chunk >> 6, kb = chunk & 63;
  const size_t off = (size_t)(rb * 16 + (l & 15)) * K_DIM + kb * 32 + (l >> 4) * 8;
  f32x4 a = *reinterpret_cast<const f32x4*>(in + off);
  f32x4 b = *reinterpret_cast<const f32x4*>(in + off + 4);
  u16x8 o;
  o[0] = f32_to_bf16_rne(a[0]); o[1] = f32_to_bf16_rne(a[1]);
  o[2] = f32_to_bf16_rne(a[2]); o[3] = f32_to_bf16_rne(a[3]);
  o[4] = f32_to_bf16_rne(b[0]); o[5] = f32_to_bf16_rne(b[1]);
  o[6] = f32_to_bf16_rne(b[2]); o[7] = f32_to_bf16_rne(b[3]);
  reinterpret_cast<u16x8*>(out)[ls] = o;
}

#define LD8(p) (*reinterpret_cast<const bf16x8*>(p))
#define VMWAIT_(n) asm volatile("s_waitcnt vmcnt(" #n ")" ::: "memory")
#define VMWAIT(n) VMWAIT_(n)
#define SCHED() __builtin_amdgcn_sched_barrier(0)

__global__ __launch_bounds__(256, 2) void gemm_reg(
    const unsigned short* __restrict__ Ac,  // chunked [M/16][K32][512]
    const unsigned short* __restrict__ Bc,  // chunked [N/16][K32][512]
    const float* __restrict__ bias,         // [N]
    float* __restrict__ C) {                // [M][N] f32
  const int tid  = threadIdx.x;
  const int lane = tid & 63;
  const int wave = tid >> 6;   // 0..3
  const int wr   = wave >> 1;  // 0..1
  const int wc   = wave & 1;   // 0..1

  // XCD swizzle: each XCD owns 2 bn-columns (W-panel 2 x 512 KB L2-resident).
  const int orig = blockIdx.x;             // 0..511
  const int wgid = (orig & 7) * 64 + (orig >> 3);
  const int bn = wgid >> 5;                // 0..15
  const int bm = wgid & 31;                // 0..31

  // rolling fragment pointers; each tile consumes 2 k-chunks (K=64) = 1024 el.
  const unsigned short* pa[4];
  const unsigned short* pb[4];
#pragma unroll
  for (int mi = 0; mi < 4; ++mi)
    pa[mi] = Ac + (size_t)(bm * 8 + wr * 4 + mi) * K32 * 512 + lane * 8;
#pragma unroll
  for (int ni = 0; ni < 4; ++ni)
    pb[ni] = Bc + (size_t)(bn * 8 + wc * 4 + ni) * K32 * 512 + lane * 8;

  const f32x4 z = {0.f, 0.f, 0.f, 0.f};
  f32x4 acc[4][4];
#pragma unroll
  for (int i = 0; i < 4; ++i)
#pragma unroll
    for (int j = 0; j < 4; ++j) acc[i][j] = z;

  bf16x8 aX[4][2], bX[4][2], aY[4][2], bY[4][2];

#define LOADSET(aS, bS) do { \
    _Pragma("unroll") \
    for (int mi = 0; mi < 4; ++mi) { \
      aS[mi][0] = LD8(pa[mi]); aS[mi][1] = LD8(pa[mi] + 512); pa[mi] += 1024; \
    } \
    _Pragma("unroll") \
    for (int ni = 0; ni < 4; ++ni) { \
      bS[ni][0] = LD8(pb[ni]); bS[ni][1] = LD8(pb[ni] + 512); pb[ni] += 1024; \
    } \
  } while (0)

#define MFMASET(aS, bS) do { \
    __builtin_amdgcn_s_setprio(1); \
    _Pragma("unroll") \
    for (int kk = 0; kk < 2; ++kk) \
      _Pragma("unroll") \
      for (int mi = 0; mi < 4; ++mi) { \
        acc[mi][0] = __builtin_amdgcn_mfma_f32_16x16x32_bf16(aS[mi][kk], bS[0][kk], acc[mi][0], 0, 0, 0); \
        acc[mi][1] = __builtin_amdgcn_mfma_f32_16x16x32_bf16(aS[mi][kk], bS[1][kk], acc[mi][1], 0, 0, 0); \
        acc[mi][2] = __builtin_amdgcn_mfma_f32_16x16x32_bf16(aS[mi][kk], bS[2][kk], acc[mi][2], 0, 0, 0); \
        acc[mi][3] = __builtin_amdgcn_mfma_f32_16x16x32_bf16(aS[mi][kk], bS[3][kk], acc[mi][3], 0, 0, 0); \
      } \
    __builtin_amdgcn_s_setprio(0); \
  } while (0)

  // Enforced pipeline step: loads for the NEXT tile are already issued;
  // wait until only those 16 remain in flight, then MFMA the CURRENT tile.
  // sched_barrier pair: loads cannot sink below the wait; MFMAs cannot
  // rise above it (register-only MFMA is not ordered by "memory").
#define PIPE_WAIT16() do { SCHED(); VMWAIT(16); SCHED(); } while (0)

  // 32 K-tiles (K=64 each), double fragment-set, enforced 1-tile look-ahead.
  LOADSET(aX, bX);                    // tile 0 in flight
#pragma unroll 1
  for (int p = 0; p < 15; ++p) {
    LOADSET(aY, bY);                  // tile 2p+1 in flight
    PIPE_WAIT16();                    // tile 2p landed
    MFMASET(aX, bX);                  // tile 2p
    LOADSET(aX, bX);                  // tile 2p+2 in flight
    PIPE_WAIT16();                    // tile 2p+1 landed
    MFMASET(aY, bY);                  // tile 2p+1
  }
  LOADSET(aY, bY);                    // tile 31 in flight
  PIPE_WAIT16();                      // tile 30 landed
  MFMASET(aX, bX);                    // tile 30
  SCHED(); VMWAIT(0); SCHED();        // tile 31 landed
  MFMASET(aY, bY);                    // tile 31

  // ---- epilogue: C/D layout col = lane&15, row = (lane>>4)*4 + r ----
  const int fr = lane & 15;
  const int qq = lane >> 4;
  const int orow0 = bm * 128 + wr * 64 + qq * 4;
  const int ocol0 = bn * 128 + wc * 64 + fr;
#pragma unroll
  for (int ni = 0; ni < 4; ++ni) {
    const int col = ocol0 + ni * 16;
    const float bv = bias[col];
#pragma unroll
    for (int mi = 0; mi < 4; ++mi) {
      const int row = orow0 + mi * 16;
#pragma unroll
      for (int r = 0; r < 4; ++r)
        C[(size_t)(row + r) * N_DIM + col] = acc[mi][ni][r] + bv;
    }
  }
#undef PIPE_WAIT16
#undef MFMASET
#undef LOADSET
}

// ---- safety fallback ----
__global__ __launch_bounds__(256) void gemm_f32_naive(
    const float* __restrict__ X, const float* __restrict__ W,
    const float* __restrict__ bias, float* __restrict__ C) {
  int o = blockIdx.x * 256 + threadIdx.x;
  if (o >= M_DIM * N_DIM) return;
  int m = o / N_DIM, n = o % N_DIM;
  const float* xr = X + (size_t)m * K_DIM;
  const float* wr = W + (size_t)n * K_DIM;
  float s = 0.f;
  for (int k = 0; k < K_DIM; ++k) s += xr[k] * wr[k];
  C[o] = s + bias[n];
}

extern "C" void kernel_launch(void* const* d_in, const int* in_sizes, int n_in,
                              void* d_out, int out_size, void* d_ws, size_t ws_size,
                              hipStream_t stream) {
  const float* x    = (const float*)d_in[0];
  const float* w    = (const float*)d_in[1];
  const float* bias = (const float*)d_in[2];
  float* out = (float*)d_out;

  const size_t x_elems = (size_t)M_DIM * K_DIM;   // 8.39M
  const size_t w_elems = (size_t)N_DIM * K_DIM;   // 4.19M
  const size_t need = (x_elems + w_elems) * sizeof(unsigned short);

  if (ws_size < need) {
    gemm_f32_naive<<<(M_DIM * N_DIM + 255) / 256, 256, 0, stream>>>(x, w, bias, out);
    return;
  }

  unsigned short* xb = (unsigned short*)d_ws;
  unsigned short* wb = xb + x_elems;

  const int xslots = (int)(x_elems / 8);           // 1,048,576
  const int totslots = (int)((x_elems + w_elems) / 8);
  cvt_chunk<<<(totslots + 255) / 256, 256, 0, stream>>>(x, w, xb, wb, xslots, totslots);

  gemm_reg<<<512, 256, 0, stream>>>(xb, wb, bias, out);
}

// Round 9
// 59.862 us; speedup vs baseline: 1.0712x; 1.0712x over previous
//
#include <hip/hip_runtime.h>
#include <hip/hip_bf16.h>

// x[4096,2048] f32, w[2048,2048] f32, bias[2048] f32, indices = permutation of
// K axis applied to BOTH operands -> cancels out of the einsum; unused.
#define M_DIM 4096
#define N_DIM 2048
#define K_DIM 2048

// 128x128 block, BK=32, 2 waves x (128x64 per wave), dbuf 32 KB LDS
// -> 4 blocks/CU co-resident (the async-overlap lever, doubled from R6).
// Per CU-step: MFMA 1242 cyc / LDS-read 1152 / L2 1170 -- balanced pipes.
#define BM 128
#define BN 128
#define BK 32
#define NT (K_DIM / BK)      // 64 K-tiles
#define A_TILE (BM * BK)     // 4096 elems = 8 KiB
#define B_TILE (BN * BK)     // 4096 elems = 8 KiB

typedef __bf16 bf16x8 __attribute__((ext_vector_type(8)));
typedef float f32x4 __attribute__((ext_vector_type(4)));
typedef unsigned short u16x8 __attribute__((ext_vector_type(8)));

__device__ __forceinline__ unsigned short f32_to_bf16_rne(float f) {
  unsigned int u = __float_as_uint(f);
  u += 0x7fffu + ((u >> 16) & 1u);
  return (unsigned short)(u >> 16);
}

// ---- merged f32 -> bf16 conversion (row-major, verified R6) ----
__global__ __launch_bounds__(256) void cvt_both(
    const float* __restrict__ x, const float* __restrict__ w,
    unsigned short* __restrict__ out, int xn8, int totn8) {
  int i = blockIdx.x * 256 + threadIdx.x;
  if (i >= totn8) return;
  const float* src = (i < xn8) ? (x + (size_t)i * 8)
                               : (w + (size_t)(i - xn8) * 8);
  f32x4 a = reinterpret_cast<const f32x4*>(src)[0];
  f32x4 b = reinterpret_cast<const f32x4*>(src)[1];
  u16x8 o;
  o[0] = f32_to_bf16_rne(a[0]); o[1] = f32_to_bf16_rne(a[1]);
  o[2] = f32_to_bf16_rne(a[2]); o[3] = f32_to_bf16_rne(a[3]);
  o[4] = f32_to_bf16_rne(b[0]); o[5] = f32_to_bf16_rne(b[1]);
  o[6] = f32_to_bf16_rne(b[2]); o[7] = f32_to_bf16_rne(b[3]);
  reinterpret_cast<u16x8*>(out)[i] = o;
}

__device__ __forceinline__ void gload_lds16(const unsigned short* g, unsigned short* l) {
  __builtin_amdgcn_global_load_lds(
      (const __attribute__((address_space(1))) unsigned int*)g,
      (__attribute__((address_space(3))) unsigned int*)l, 16, 0, 0);
}

#define LD8(p) (*reinterpret_cast<const bf16x8*>(p))
#define VMWAIT0() asm volatile("s_waitcnt vmcnt(0)" ::: "memory")
#define SBAR() __builtin_amdgcn_s_barrier()
#define SCHED() __builtin_amdgcn_sched_barrier(0)

__global__ __launch_bounds__(128, 2) void gemm_4b(
    const unsigned short* __restrict__ A,   // [M][K] bf16 bits
    const unsigned short* __restrict__ B,   // [N][K] bf16 bits
    const float* __restrict__ bias,         // [N]
    float* __restrict__ C) {                // [M][N] f32
  __shared__ unsigned short As[2 * A_TILE]; // 16 KiB
  __shared__ unsigned short Bs[2 * B_TILE]; // 16 KiB

  const int tid  = threadIdx.x;   // 0..127
  const int lane = tid & 63;
  const int wc   = tid >> 6;      // wave 0..1 = N-half

  // 2D XCD swizzle: each XCD owns an 8bm x 8bn chunk (panel reuse in L2).
  const int orig = blockIdx.x;    // 0..511
  const int xcd  = orig & 7;
  const int idx  = orig >> 3;     // 0..63
  const int bm   = (xcd & 3) * 8 + (idx & 7);   // 0..31
  const int bn   = (xcd >> 2) * 8 + (idx >> 3); // 0..15

  // ---- staging: 128 thr x 16B = 32 rows x 64B per gload issue ----
  // A: 4 issues of 32 rows; B: 4 issues. 8 gloads/thread per K-tile.
  const int srow   = tid >> 2;                 // 0..31
  const int schunk = (tid & 3) ^ (srow & 3);   // pre-swizzled global source
  const unsigned short* Ag[4];
  const unsigned short* Bg[4];
#pragma unroll
  for (int j = 0; j < 4; ++j) {
    Ag[j] = A + (size_t)(bm * BM + j * 32 + srow) * K_DIM + schunk * 8;
    Bg[j] = B + (size_t)(bn * BN + j * 32 + srow) * K_DIM + schunk * 8;
  }

#define STAGE(buf, k0) do { \
    unsigned short* _da = &As[(buf) * A_TILE + tid * 8]; \
    unsigned short* _db = &Bs[(buf) * B_TILE + tid * 8]; \
    gload_lds16(Ag[0] + (k0), _da); \
    gload_lds16(Ag[1] + (k0), _da + 1024); \
    gload_lds16(Ag[2] + (k0), _da + 2048); \
    gload_lds16(Ag[3] + (k0), _da + 3072); \
    gload_lds16(Bg[0] + (k0), _db); \
    gload_lds16(Bg[1] + (k0), _db + 1024); \
    gload_lds16(Bg[2] + (k0), _db + 2048); \
    gload_lds16(Bg[3] + (k0), _db + 3072); \
  } while (0)

  // ---- ds_read offsets (elements): row-major [128][32] per buffer,
  // element (r,k): addr = r*32 + ((k>>3) ^ (r&3))*8 + (k&7).
  const int fr = lane & 15;
  const int qq = lane >> 4;
  const int xr = fr & 3;
  int aoff[8], boff[4];
#pragma unroll
  for (int mi = 0; mi < 8; ++mi)
    aoff[mi] = ((mi * 16 + fr) * 4 + (qq ^ xr)) * 8;
#pragma unroll
  for (int ni = 0; ni < 4; ++ni)
    boff[ni] = ((wc * 64 + ni * 16 + fr) * 4 + (qq ^ xr)) * 8;

  const f32x4 z = {0.f, 0.f, 0.f, 0.f};
  f32x4 acc[8][4];
#pragma unroll
  for (int i = 0; i < 8; ++i)
#pragma unroll
    for (int j = 0; j < 4; ++j) acc[i][j] = z;

  bf16x8 av[8], bv[4];

#define READ_SET(bufi) do { \
    const unsigned short* Asb = &As[(bufi) * A_TILE]; \
    const unsigned short* Bsb = &Bs[(bufi) * B_TILE]; \
    bv[0] = LD8(Bsb + boff[0]); bv[1] = LD8(Bsb + boff[1]); \
    bv[2] = LD8(Bsb + boff[2]); bv[3] = LD8(Bsb + boff[3]); \
    av[0] = LD8(Asb + aoff[0]); av[1] = LD8(Asb + aoff[1]); \
    av[2] = LD8(Asb + aoff[2]); av[3] = LD8(Asb + aoff[3]); \
    av[4] = LD8(Asb + aoff[4]); av[5] = LD8(Asb + aoff[5]); \
    av[6] = LD8(Asb + aoff[6]); av[7] = LD8(Asb + aoff[7]); \
  } while (0)

#define MFMA_ALL() do { \
    __builtin_amdgcn_s_setprio(1); \
    _Pragma("unroll") \
    for (int mi = 0; mi < 8; ++mi) { \
      acc[mi][0] = __builtin_amdgcn_mfma_f32_16x16x32_bf16(av[mi], bv[0], acc[mi][0], 0, 0, 0); \
      acc[mi][1] = __builtin_amdgcn_mfma_f32_16x16x32_bf16(av[mi], bv[1], acc[mi][1], 0, 0, 0); \
      acc[mi][2] = __builtin_amdgcn_mfma_f32_16x16x32_bf16(av[mi], bv[2], acc[mi][2], 0, 0, 0); \
      acc[mi][3] = __builtin_amdgcn_mfma_f32_16x16x32_bf16(av[mi], bv[3], acc[mi][3], 0, 0, 0); \
    } \
    __builtin_amdgcn_s_setprio(0); \
  } while (0)

  // Iteration t (parity p): regs hold tile t (read last iter from buf p).
  // Stage t+1 into buf p^1 (its readers finished before the PREVIOUS
  // barrier); MFMA tile t; drain+barrier; read tile t+1 regs from p^1.
  // No sched pin between READ_SET and next MFMA -- compiler interleaves.
#define ITER(p_, t_) do { \
    STAGE((p_) ^ 1, ((t_) + 1) * BK); \
    MFMA_ALL(); \
    VMWAIT0(); \
    SBAR(); \
    SCHED(); \
    READ_SET((p_) ^ 1); \
  } while (0)

  // prologue: stage tile 0 into buf0, wait, read tile-0 regs.
  STAGE(0, 0);
  VMWAIT0();
  SBAR();
  SCHED();
  READ_SET(0);

  // main loop: tiles 0..61 (stage 1..62), unrolled by 2 for literal parity.
#pragma unroll 1
  for (int s = 0; s < 31; ++s) {
    ITER(0, 2 * s);
    ITER(1, 2 * s + 1);
  }
  ITER(0, 62);   // stages tile 63 -> buf1, reads tile-63 regs
  MFMA_ALL();    // tile 63

  // ---- epilogue: C/D layout col = lane&15, row = (lane>>4)*4 + r ----
  const int orow0 = bm * BM + qq * 4;
  const int ocol0 = bn * BN + wc * 64 + fr;
#pragma unroll
  for (int ni = 0; ni < 4; ++ni) {
    const int col = ocol0 + ni * 16;
    const float bvv = bias[col];
#pragma unroll
    for (int mi = 0; mi < 8; ++mi) {
      const int row = orow0 + mi * 16;
#pragma unroll
      for (int r = 0; r < 4; ++r)
        C[(size_t)(row + r) * N_DIM + col] = acc[mi][ni][r] + bvv;
    }
  }
#undef ITER
#undef MFMA_ALL
#undef READ_SET
#undef STAGE
}

// ---- safety fallback ----
__global__ __launch_bounds__(256) void gemm_f32_naive(
    const float* __restrict__ X, const float* __restrict__ W,
    const float* __restrict__ bias, float* __restrict__ C) {
  int o = blockIdx.x * 256 + threadIdx.x;
  if (o >= M_DIM * N_DIM) return;
  int m = o / N_DIM, n = o % N_DIM;
  const float* xr = X + (size_t)m * K_DIM;
  const float* wr = W + (size_t)n * K_DIM;
  float s = 0.f;
  for (int k = 0; k < K_DIM; ++k) s += xr[k] * wr[k];
  C[o] = s + bias[n];
}

extern "C" void kernel_launch(void* const* d_in, const int* in_sizes, int n_in,
                              void* d_out, int out_size, void* d_ws, size_t ws_size,
                              hipStream_t stream) {
  const float* x    = (const float*)d_in[0];
  const float* w    = (const float*)d_in[1];
  const float* bias = (const float*)d_in[2];
  float* out = (float*)d_out;

  const size_t x_elems = (size_t)M_DIM * K_DIM;
  const size_t w_elems = (size_t)N_DIM * K_DIM;
  const size_t need = (x_elems + w_elems) * sizeof(unsigned short);

  if (ws_size < need) {
    gemm_f32_naive<<<(M_DIM * N_DIM + 255) / 256, 256, 0, stream>>>(x, w, bias, out);
    return;
  }

  unsigned short* xb = (unsigned short*)d_ws;
  unsigned short* wb = xb + x_elems;

  const int xn8 = (int)(x_elems / 8);
  const int totn8 = (int)((x_elems + w_elems) / 8);
  cvt_both<<<(totn8 + 255) / 256, 256, 0, stream>>>(x, w, xb, xn8, totn8);

  gemm_4b<<<512, 128, 0, stream>>>(xb, wb, bias, out);
}